// Round 11
// baseline (111.815 us; speedup 1.0000x reference)
//
#include <hip/hip_runtime.h>
#include <math.h>

// Problem constants
#define BH 2
#define HH 96
#define WW 96
#define NPIX (BH*HH*WW)

// Attention tile geometry: 8x4 pixels, halo 14x10 = 140 (pad 160)
#define TH 8
#define TW 4
#define NH 140
#define NHP 160

#define NEGBIG (-3.0e38f)

typedef __attribute__((ext_vector_type(8))) short short8;
typedef __attribute__((ext_vector_type(4))) float f32x4;

__device__ __forceinline__ unsigned short f2bf(float f) {
    union { float f; unsigned u; } a; a.f = f;
    return (unsigned short)((a.u + 0x7FFFu + ((a.u >> 16) & 1u)) >> 16);
}
__device__ __forceinline__ unsigned packbf(float x, float y) {
    return (unsigned)f2bf(x) | ((unsigned)f2bf(y) << 16);
}

// ---------------------------------------------------------------------------
// Dispatch 1: q/k proj + V->bf16 + WvT (identical to R10).
// ---------------------------------------------------------------------------
#define WT_STRIDE 136   // u16, 16B-aligned rows

__global__ __launch_bounds__(256) void prep_proj_kernel(
    const float* __restrict__ Qg, const float* __restrict__ Kg,
    const float* __restrict__ V,  const float* __restrict__ Wq,
    const float* __restrict__ bq, const float* __restrict__ Wk,
    const float* __restrict__ bk, const float* __restrict__ Wv,
    unsigned short* __restrict__ q_bf, unsigned short* __restrict__ k_bf,
    unsigned short* __restrict__ v_bf, unsigned short* __restrict__ WvT)
{
    __shared__ unsigned short WT[64 * WT_STRIDE];   // 17.4 KB
    const int bid = blockIdx.x;
    const int tid = threadIdx.x;

    if (bid < 576) {
        const bool isq = bid < 288;
        const float* __restrict__ X   = isq ? Qg : Kg;
        const float* __restrict__ Wt  = isq ? Wq : Wk;
        const float* __restrict__ bia = isq ? bq : bk;
        unsigned short* __restrict__ Y = isq ? q_bf : k_bf;

        // stage W[128][64] fp32 -> WT[64][128] bf16 (transposed), coalesced
        {
            const float4* __restrict__ W4 = reinterpret_cast<const float4*>(Wt);
            #pragma unroll
            for (int i = 0; i < 8; ++i) {
                const int e  = tid + 256 * i;     // float4 idx 0..2047
                const int k  = e >> 4;            // 0..127
                const int n4 = (e & 15) * 4;      // 0..60
                const float4 v = W4[e];
                WT[(n4 + 0) * WT_STRIDE + k] = f2bf(v.x);
                WT[(n4 + 1) * WT_STRIDE + k] = f2bf(v.y);
                WT[(n4 + 2) * WT_STRIDE + k] = f2bf(v.z);
                WT[(n4 + 3) * WT_STRIDE + k] = f2bf(v.w);
            }
        }
        __syncthreads();

        const int lane = tid & 63;
        const int wvv  = tid >> 6;
        const int row0 = ((bid % 288) * 4 + wvv) * 16;
        const int qd = lane >> 4, m = lane & 15;

        short8 afr[4];
        #pragma unroll
        for (int ks = 0; ks < 4; ++ks) {
            const float4* __restrict__ src = reinterpret_cast<const float4*>(
                X + (size_t)(row0 + m) * 128 + ks * 32 + qd * 8);
            const float4 a0 = src[0], a1 = src[1];
            short8 f;
            f[0] = (short)f2bf(a0.x); f[1] = (short)f2bf(a0.y);
            f[2] = (short)f2bf(a0.z); f[3] = (short)f2bf(a0.w);
            f[4] = (short)f2bf(a1.x); f[5] = (short)f2bf(a1.y);
            f[6] = (short)f2bf(a1.z); f[7] = (short)f2bf(a1.w);
            afr[ks] = f;
        }

        #pragma unroll
        for (int n = 0; n < 4; ++n) {
            f32x4 acc = {};
            #pragma unroll
            for (int ks = 0; ks < 4; ++ks) {
                const short8 bfr = *reinterpret_cast<const short8*>(
                    &WT[(n * 16 + m) * WT_STRIDE + ks * 32 + qd * 8]);
                acc = __builtin_amdgcn_mfma_f32_16x16x32_bf16(afr[ks], bfr, acc, 0, 0, 0);
            }
            const int col = n * 16 + m;
            const float bb = bia[col];
            #pragma unroll
            for (int r = 0; r < 4; ++r)
                Y[(size_t)(row0 + qd * 4 + r) * 64 + col] = f2bf(acc[r] + bb);
        }
    } else if (bid < 1728) {
        const int idx = (bid - 576) * 256 + tid;          // 0..294911
        const float4* __restrict__ V4 = reinterpret_cast<const float4*>(V);
        const float4 a = V4[idx * 2], b = V4[idx * 2 + 1];
        uint4 o;
        o.x = packbf(a.x, a.y); o.y = packbf(a.z, a.w);
        o.z = packbf(b.x, b.y); o.w = packbf(b.z, b.w);
        reinterpret_cast<uint4*>(v_bf)[idx] = o;
    } else {
        const int base = (bid - 1728) * 1024 + tid * 4;
        #pragma unroll
        for (int i = 0; i < 4; ++i) {
            const int e = base + i;                        // e = n*128 + k
            WvT[e] = f2bf(Wv[(e & 127) * 128 + (e >> 7)]);
        }
    }
}

// ---------------------------------------------------------------------------
// Dispatch 2: neighborhood attention + out-projection (R10 structure).
// R11 change: PV's V B-frags are PREFETCHED into registers right after B1
// (they depend only on the offset table, not on P) so their L2 latency is
// hidden by the softmax merge + P-write + B2. exp guards dropped (center
// pixel always valid -> finite row max; exp underflow handles the rest).
// LDS (u16): PS[32][168] @0 | AS[32][136] @5376 | SM 256f @9728 |
//            offs 160 int @10240 -> 10560 u16 = 21120 B.
// ---------------------------------------------------------------------------
#define PS_OFF 0
#define PS_STRIDE 168
#define AS_OFF 5376
#define AS_STRIDE 136
#define SM_OFF 9728
#define OFF_OFF 10240
#define LDS_N 10560

__global__ __launch_bounds__(512) void attn_kernel(
    const unsigned short* __restrict__ q_bf, const unsigned short* __restrict__ k_bf,
    const unsigned short* __restrict__ v_bf, const unsigned short* __restrict__ WvT,
    const float* __restrict__ bv, float* __restrict__ out)
{
    __shared__ unsigned short lds[LDS_N];
    const int tid  = threadIdx.x;
    const int lane = tid & 63;
    const int wv   = tid >> 6;     // 0..7
    const int mt   = wv & 1;
    const int ng   = wv >> 1;      // 0..3

    const int bid  = blockIdx.x;   // 576
    const int bimg = bid / 288;
    const int tidx = bid % 288;
    const int ty = tidx / 24, tx = tidx % 24;
    const int y0 = ty * TH, x0 = tx * TW;

    const int qd = lane >> 4, m = lane & 15;

    int*   __restrict__ offsI = reinterpret_cast<int*>(&lds[OFF_OFF]);
    float* __restrict__ smf   = reinterpret_cast<float*>(&lds[SM_OFF]);

    // ---- offs table (first consumed after B1) ----
    if (tid < NHP) {
        const int r = tid;
        const int hy = (r * 6554) >> 16;            // r/10
        const int hx = r - hy * 10;
        const int iy = y0 - 3 + hy, ix = x0 - 3 + hx;
        int o = 0;                                  // pre-clamped (pad -> 0)
        if (((unsigned)iy < HH) & ((unsigned)ix < WW) & (r < NH))
            o = (bimg * HH + iy) * WW + ix;
        offsI[r] = o;
    }

    // ---- q A-frags ----
    short8 qa[2];
    {
        const int py = mt * 4 + (m >> 2), px = m & 3;
        const size_t gq = (size_t)(bimg * HH + y0 + py) * WW + (x0 + px);
        #pragma unroll
        for (int ks = 0; ks < 2; ++ks)
            qa[ks] = *reinterpret_cast<const short8*>(q_bf + gq * 64 + ks * 32 + qd * 8);
    }

    // ---- scores: wave's n-tiles ----
    const int ntbase = (ng < 2) ? ng * 3 : 6 + (ng - 2) * 2;
    const int ntcnt  = (ng < 2) ? 3 : 2;

    f32x4 sc[3];
    #pragma unroll
    for (int n5 = 0; n5 < 3; ++n5) {
        if (n5 >= ntcnt) break;
        const int h  = (ntbase + n5) * 16 + m;
        const int hy = (h * 6554) >> 16;
        const int hx = h - hy * 10;
        const int iy = y0 - 3 + hy, ix = x0 - 3 + hx;
        const bool ok = ((unsigned)iy < HH) & ((unsigned)ix < WW) & (h < NH);
        const size_t ob = ok ? (size_t)((bimg * HH + iy) * WW + ix) * 64 : 0;
        f32x4 a = {};
        #pragma unroll
        for (int ks = 0; ks < 2; ++ks) {
            const short8 bfr = *reinterpret_cast<const short8*>(k_bf + ob + ks * 32 + qd * 8);
            a = __builtin_amdgcn_mfma_f32_16x16x32_bf16(qa[ks], bfr, a, 0, 0, 0);
        }
        sc[n5] = a;
    }

    // ---- mask + per-group softmax partials ----
    float mx[4] = {NEGBIG, NEGBIG, NEGBIG, NEGBIG};
    #pragma unroll
    for (int n5 = 0; n5 < 3; ++n5) {
        if (n5 >= ntcnt) break;
        const int h  = (ntbase + n5) * 16 + m;
        const int hy = (h * 6554) >> 16;
        const int hx = h - hy * 10;
        const int iy = y0 - 3 + hy, ix = x0 - 3 + hx;
        const bool imgok = ((unsigned)iy < HH) & ((unsigned)ix < WW) & (h < NH);
        const int py = mt * 4 + qd;
        #pragma unroll
        for (int r = 0; r < 4; ++r) {
            const bool ok = imgok & ((unsigned)(hy - py) <= 6u) & ((unsigned)(hx - r) <= 6u);
            const float s = ok ? sc[n5][r] * 0.125f : NEGBIG;
            sc[n5][r] = s;
            mx[r] = fmaxf(mx[r], s);
        }
    }
    #pragma unroll
    for (int r = 0; r < 4; ++r)
        #pragma unroll
        for (int off = 1; off < 16; off <<= 1)
            mx[r] = fmaxf(mx[r], __shfl_xor(mx[r], off));

    float sm[4] = {0.f, 0.f, 0.f, 0.f};
    #pragma unroll
    for (int n5 = 0; n5 < 3; ++n5) {
        if (n5 >= ntcnt) break;
        #pragma unroll
        for (int r = 0; r < 4; ++r) {
            const float e = __expf(sc[n5][r] - mx[r]);   // underflow -> 0 for masked
            sc[n5][r] = e;
            sm[r] += e;
        }
    }
    #pragma unroll
    for (int r = 0; r < 4; ++r)
        #pragma unroll
        for (int off = 1; off < 16; off <<= 1)
            sm[r] += __shfl_xor(sm[r], off);

    if (m == 0) {
        #pragma unroll
        for (int r = 0; r < 4; ++r) {
            const int row = mt * 16 + qd * 4 + r;
            smf[row * 4 + ng]       = mx[r];
            smf[128 + row * 4 + ng] = sm[r];
        }
    }
    __syncthreads();   // B1: SM partials + offs ready

    // ---- PREFETCH PV B-frags (depend only on offs, NOT on P) ----
    short8 vfr[5][2];
    #pragma unroll
    for (int ks = 0; ks < 5; ++ks) {
        const int kbase = ks * 32 + qd * 8;
        const unsigned short* vb[8];
        #pragma unroll
        for (int j = 0; j < 8; ++j)
            vb[j] = v_bf + (size_t)offsI[kbase + j] * 128;
        #pragma unroll
        for (int n2 = 0; n2 < 2; ++n2) {
            const int ch = (ng * 2 + n2) * 16 + m;
            short8 bfr;
            #pragma unroll
            for (int j = 0; j < 8; ++j)
                bfr[j] = (short)vb[j][ch];
            vfr[ks][n2] = bfr;
        }
    }

    // ---- merge 4-way partials (overlaps with gathers in flight) ----
    float fac[4];
    #pragma unroll
    for (int r = 0; r < 4; ++r) {
        const int row = mt * 16 + qd * 4 + r;
        float M = smf[row * 4 + 0];
        M = fmaxf(M, smf[row * 4 + 1]);
        M = fmaxf(M, smf[row * 4 + 2]);
        M = fmaxf(M, smf[row * 4 + 3]);
        float S = 0.f;
        #pragma unroll
        for (int g = 0; g < 4; ++g)
            S += smf[128 + row * 4 + g] * __expf(smf[row * 4 + g] - M);
        fac[r] = __expf(mx[r] - M) / S;
    }

    // ---- write P quarter (bf16) ----
    #pragma unroll
    for (int n5 = 0; n5 < 3; ++n5) {
        if (n5 >= ntcnt) break;
        #pragma unroll
        for (int r = 0; r < 4; ++r) {
            const int row = mt * 16 + qd * 4 + r;
            const int col = (ntbase + n5) * 16 + m;
            lds[PS_OFF + row * PS_STRIDE + col] = f2bf(sc[n5][r] * fac[r]);
        }
    }
    __syncthreads();   // B2: P complete

    // ---- PV: A = P (LDS b128), B = prefetched registers ----
    short8 pa[5];
    #pragma unroll
    for (int ks = 0; ks < 5; ++ks)
        pa[ks] = *reinterpret_cast<const short8*>(
            &lds[PS_OFF + (mt * 16 + m) * PS_STRIDE + ks * 32 + qd * 8]);

    f32x4 oacc[2] = {};
    #pragma unroll
    for (int ks = 0; ks < 5; ++ks)
        #pragma unroll
        for (int n2 = 0; n2 < 2; ++n2)
            oacc[n2] = __builtin_amdgcn_mfma_f32_16x16x32_bf16(
                pa[ks], vfr[ks][n2], oacc[n2], 0, 0, 0);

    // ---- att -> AS ----
    #pragma unroll
    for (int n2 = 0; n2 < 2; ++n2)
        #pragma unroll
        for (int r = 0; r < 4; ++r) {
            const int row = mt * 16 + qd * 4 + r;
            const int col = (ng * 2 + n2) * 16 + m;
            lds[AS_OFF + row * AS_STRIDE + col] = f2bf(oacc[n2][r]);
        }
    __syncthreads();   // B3: att complete

    // ---- out-proj + bias + relu ----
    short8 aa[4];
    #pragma unroll
    for (int ks = 0; ks < 4; ++ks)
        aa[ks] = *reinterpret_cast<const short8*>(
            &lds[AS_OFF + (mt * 16 + m) * AS_STRIDE + ks * 32 + qd * 8]);

    #pragma unroll
    for (int n2 = 0; n2 < 2; ++n2) {
        const int nt = ng * 2 + n2;
        f32x4 a = {};
        #pragma unroll
        for (int ks = 0; ks < 4; ++ks) {
            const short8 bfr = *reinterpret_cast<const short8*>(
                WvT + (nt * 16 + m) * 128 + ks * 32 + qd * 8);
            a = __builtin_amdgcn_mfma_f32_16x16x32_bf16(aa[ks], bfr, a, 0, 0, 0);
        }
        const int col = nt * 16 + m;
        const float bb = bv[col];
        #pragma unroll
        for (int r = 0; r < 4; ++r) {
            const int py = mt * 4 + qd, px = r;
            const size_t gp = (size_t)(bimg * HH + y0 + py) * WW + (x0 + px);
            out[gp * 128 + col] = fmaxf(a[r] + bb, 0.f);
        }
    }
}

extern "C" void kernel_launch(void* const* d_in, const int* in_sizes, int n_in,
                              void* d_out, int out_size, void* d_ws, size_t ws_size,
                              hipStream_t stream)
{
    const float* Q  = (const float*)d_in[0];
    const float* K  = (const float*)d_in[1];
    const float* V  = (const float*)d_in[2];
    const float* Wq = (const float*)d_in[3];
    const float* bq = (const float*)d_in[4];
    const float* Wk = (const float*)d_in[5];
    const float* bk = (const float*)d_in[6];
    const float* Wv = (const float*)d_in[7];
    const float* bv = (const float*)d_in[8];
    float* out = (float*)d_out;

    unsigned short* wbase = (unsigned short*)d_ws;
    unsigned short* WvT   = wbase + 16384;
    unsigned short* q_bf  = wbase + 32768;             // NPIX*64 bf16
    unsigned short* k_bf  = q_bf + (size_t)NPIX * 64;  // NPIX*64 bf16
    unsigned short* v_bf  = k_bf + (size_t)NPIX * 64;  // NPIX*128 bf16

    prep_proj_kernel<<<1744, 256, 0, stream>>>(Q, K, V, Wq, bq, Wk, bk, Wv,
                                               q_bf, k_bf, v_bf, WvT);
    attn_kernel<<<576, 512, 0, stream>>>(q_bf, k_bf, v_bf, WvT, bv, out);
}